// Round 1
// baseline (117.720 us; speedup 1.0000x reference)
//
#include <hip/hip_runtime.h>
#include <hip/hip_bf16.h>

// MoE conv via bf16 MFMA implicit GEMM, tap-decomposed — barrier-free main loop.
// x: [32,64,64,64] f32  idx: [32] i32  Wc: [4,128,64,3,3] f32  bc: [4,128] f32
// out: [32,128,64,64] f32
//
// Pre-kernel: transpose Wc -> d_ws bf16 [e][tap][ich(8)][oc(128)][icl(8)] (576 KB).
// NEW: gather-reads (stride 36B, L2-served) + one coalesced 16B store per thread.
// Main: 512 threads = 8 waves: 1 sample x 128 oc x (4 rows x 64 cols).
// Wave = 64oc x 64px: 2x2 accs of mfma_f32_32x32x16_bf16.
// NEW: A-fragments (weights) load per-lane DIRECTLY from global (L1/L2-hot:
// 16 KB/tap shared by all blocks of the same expert), double-buffered one
// (tap,ks)-step ahead in 16 VGPRs. No weight LDS, no per-tap barriers — a
// single __syncthreads() after x staging; waves free-run through all 36 MFMA
// steps so stage/compute/write phases overlap across the 2 blocks/CU.
// LDS 51.2 KB; __launch_bounds__(512,4) caps VGPR<=128 -> 16 waves/CU.

#define IC 64
#define OC 128
#define HH 64
#define WW 64

typedef short short8 __attribute__((ext_vector_type(8)));
typedef ushort ushort8 __attribute__((ext_vector_type(8)));
typedef float float16 __attribute__((ext_vector_type(16)));

static __device__ __forceinline__ ushort f2bf(float v) {
    __hip_bfloat16 h = __float2bfloat16(v);
    return *(ushort*)&h;
}

// ---------------- pre-kernel: reorder + convert weights ----------------
// One ushort8 (16B, coalesced) store per thread; 8 gather reads stride 36B.
// u = ((e*9 + tap)*8 + ich)*128 + oc  (oc fastest -> consecutive lanes store
// consecutive 16B). Reads hit L2 (1.18 MB working set).
__global__ __launch_bounds__(256)
void reorder_w(const float* __restrict__ Wc, ushort* __restrict__ wout) {
    const int u   = blockIdx.x * 256 + threadIdx.x;   // 0 .. 36,863
    const int oc  = u & 127;
    const int ich = (u >> 7) & 7;
    const int et  = u >> 10;                          // e*9 + tap, 0..35
    const int tap = et % 9;
    const int e   = et / 9;
    const float* src = Wc + (((size_t)(e * 128 + oc) * 64 + ich * 8) * 9 + tap);
    ushort8 v;
#pragma unroll
    for (int j = 0; j < 8; ++j) v[j] = f2bf(src[j * 9]);
    *(ushort8*)(wout + (size_t)u * 8) = v;
}

// ---------------- main kernel ----------------
__global__ __launch_bounds__(512, 4)
void moe_conv_mfma(const float* __restrict__ x, const int* __restrict__ idx,
                   const ushort* __restrict__ wre, const float* __restrict__ bc,
                   float* __restrict__ out) {
    __shared__ __align__(16) ushort xs[6 * 8 * 66 * 8];  // [r][ich][hc][icl] 50688 B
    __shared__ float bias[128];

    const int t    = threadIdx.x;
    const int rq   = blockIdx.x;          // row quad 0..15
    const int b    = blockIdx.y;          // sample
    const int row0 = rq * 4;
    const int e    = ((unsigned)idx[b]) & 3;   // hardened expert index

    // --- per-lane MFMA coordinates ---
    const int lane31 = t & 31;
    const int lhi    = (t >> 5) & 1;
    const int wv     = t >> 6;            // 0..7
    const int w0     = wv & 1;            // oc half
    const int pr     = wv >> 1;           // output row within quad, 0..3

    // Per-lane weight base: element ((tap*8 + ks*2 + lhi)*128 + w0*64 + lane31)*8
    // = wsrc + s*2048 (+256 for a1), s = tap*4 + ks. 16B per lane, lanes
    // consecutive -> two 512B segments per load instruction.
    const ushort* wsrc = wre + (size_t)e * 9 * 8192
                       + ((size_t)lhi * 128 + w0 * 64 + lane31) * 8;

    // issue step-0 A loads now: L2 latency hides under the x staging below
    short8 a0c = *(const short8*)(wsrc);
    short8 a1c = *(const short8*)(wsrc + 256);

    // --- halo-column zeros (hc = 0, 65) + bias stage ---
    if (t < 192) {  // r(6) x ich(8) x side(2) x q(2)
        const int r = t >> 5, rem = t & 31;
        const int ich = rem >> 2, side = (rem >> 1) & 1, q = rem & 1;
        const int hc = side ? 65 : 0;
        ushort4 z = {0, 0, 0, 0};
        *(ushort4*)&xs[(((r * 8 + ich) * 66 + hc) * 8 + q * 4)] = z;
    } else if (t < 320) {
        bias[t - 192] = bc[e * OC + (t - 192)];
    }

    // --- x staging: fp32 [ic][h][w] -> bf16 [r(6)][ich][hc][icl] ---
    const float* xb = x + (size_t)b * IC * HH * WW;
    {
        const int gc   = t & 63;          // coalesced lane = w
        const int csel = t >> 6;          // 0..7
#pragma unroll
        for (int it = 0; it < 12; ++it) {
            const int combo = it * 8 + csel;       // 0..95 = r(6) x ich(8) x q(2)
            const int r = combo >> 4, rem = combo & 15;
            const int ich = rem >> 1, q = rem & 1;
            const int gr = row0 - 1 + r;
            ushort4 u = {0, 0, 0, 0};
            if ((unsigned)gr < (unsigned)HH) {
                const int ic0 = ich * 8 + q * 4;
                u.x = f2bf(xb[((ic0 + 0) * HH + gr) * WW + gc]);
                u.y = f2bf(xb[((ic0 + 1) * HH + gr) * WW + gc]);
                u.z = f2bf(xb[((ic0 + 2) * HH + gr) * WW + gc]);
                u.w = f2bf(xb[((ic0 + 3) * HH + gr) * WW + gc]);
            }
            *(ushort4*)&xs[(((r * 8 + ich) * 66 + (gc + 1)) * 8 + q * 4)] = u;
        }
    }

    float16 acc[2][2];
#pragma unroll
    for (int a = 0; a < 2; ++a)
#pragma unroll
        for (int cg = 0; cg < 2; ++cg)
#pragma unroll
            for (int r = 0; r < 16; ++r) acc[a][cg][r] = 0.0f;

    __syncthreads();   // the ONLY barrier: xs + bias visible to all waves

    // Lane-constant part of the xs B-fragment address; per-step remainder is a
    // compile-time constant folded into the ds_read offset immediate.
    const int xbase = ((pr * 8 + lhi) * 66 + lane31) * 8;

    // --- 36 free-running MFMA steps (tap = s>>2, ks = s&3), A dbuf'd 1 ahead ---
#pragma unroll
    for (int s = 0; s < 36; ++s) {
        const int tap = s >> 2, ks = s & 3;
        const int kh  = tap / 3, kw = tap - kh * 3;
        const int off = ((kh * 8 + ks * 2) * 66 + kw) * 8;   // step-const

        const short8 b0 = *(const short8*)&xs[xbase + off];
        const short8 b1 = *(const short8*)&xs[xbase + off + 256];  // +32 px

        short8 a0n, a1n;
        if (s < 35) {  // prefetch next step's A-frags; fly under the MFMAs
            a0n = *(const short8*)(wsrc + (s + 1) * 2048);
            a1n = *(const short8*)(wsrc + (s + 1) * 2048 + 256);
        }

        acc[0][0] = __builtin_amdgcn_mfma_f32_32x32x16_bf16(a0c, b0, acc[0][0], 0, 0, 0);
        acc[0][1] = __builtin_amdgcn_mfma_f32_32x32x16_bf16(a0c, b1, acc[0][1], 0, 0, 0);
        acc[1][0] = __builtin_amdgcn_mfma_f32_32x32x16_bf16(a1c, b0, acc[1][0], 0, 0, 0);
        acc[1][1] = __builtin_amdgcn_mfma_f32_32x32x16_bf16(a1c, b1, acc[1][1], 0, 0, 0);

        if (s < 35) { a0c = a0n; a1c = a1n; }
    }

    // --- epilogue: C/D layout col=lane&31, row=(reg&3)+8*(reg>>2)+4*(lane>>5) ---
#pragma unroll
    for (int a = 0; a < 2; ++a) {
        const int ocb = w0 * 64 + a * 32 + 4 * lhi;
#pragma unroll
        for (int reg = 0; reg < 16; ++reg) {
            const int oc = ocb + (reg & 3) + 8 * (reg >> 2);
            const float bv = bias[oc];
            const size_t base = (((size_t)b * OC + oc) * HH + (row0 + pr)) * WW;
            out[base + lane31]      = acc[a][0][reg] + bv;
            out[base + 32 + lane31] = acc[a][1][reg] + bv;
        }
    }
}

extern "C" void kernel_launch(void* const* d_in, const int* in_sizes, int n_in,
                              void* d_out, int out_size, void* d_ws, size_t ws_size,
                              hipStream_t stream) {
    const float* x   = (const float*)d_in[0];
    const int*   idx = (const int*)d_in[1];
    const float* Wc  = (const float*)d_in[2];
    const float* bc  = (const float*)d_in[3];
    float* out  = (float*)d_out;
    ushort* wre = (ushort*)d_ws;   // 294,912 bf16 = 576 KB scratch

    reorder_w<<<144, 256, 0, stream>>>(Wc, wre);    // 144*256*8 = 294,912 = |Wc|
    dim3 grid(16, 32);             // row-quads x samples = 512 blocks
    moe_conv_mfma<<<grid, 512, 0, stream>>>(x, idx, wre, bc, out);
}

// Round 2
// 112.507 us; speedup vs baseline: 1.0463x; 1.0463x over previous
//
#include <hip/hip_runtime.h>
#include <hip/hip_bf16.h>

// MoE conv via bf16 MFMA implicit GEMM, tap-decomposed — 4-blocks/CU structure.
// x: [32,64,64,64] f32  idx: [32] i32  Wc: [4,128,64,3,3] f32  bc: [4,128] f32
// out: [32,128,64,64] f32
//
// Pre-kernel (NEW): LDS-transpose reorder. 128 blocks; each reads a CONTIGUOUS
// 2304-float slice of Wc (one expert x 4 oc), transposes through padded LDS,
// emits coalesced ushort8 stores. Target layout [e][tap][ich8][oc128][icl8].
// Round-1 version (8x stride-36B gathers, 144 blocks) cost ~25-30 us.
//
// Main (NEW): 1024 blocks x 256 thr (4 waves) = 2 output rows x 128 oc x 64 px.
// xs shrinks to 33.8 KB -> 4 blocks/CU (vs 2): independent blocks drift out of
// phase so staging/epilogue memory ops of one block overlap MFMA of another.
// Weights load per-lane from global (L1/L2-hot), dbuf depth-1 (reg budget:
// 60 VGPR + 64 acc = 124 <= 128 for 4 waves/SIMD). T1 XCD swizzle: each XCD
// owns 4 whole samples -> halo rows + x-slice are same-L2. T5 setprio around
// the MFMA quad (phase diversity now exists).

#define IC 64
#define OC 128
#define HH 64
#define WW 64

typedef short short8 __attribute__((ext_vector_type(8)));
typedef ushort ushort8 __attribute__((ext_vector_type(8)));
typedef float float16 __attribute__((ext_vector_type(16)));

static __device__ __forceinline__ ushort f2bf(float v) {
    __hip_bfloat16 h = __float2bfloat16(v);
    return *(ushort*)&h;
}

// ---------------- pre-kernel: reorder + convert weights ----------------
// Block = (e, oc-group of 4). Phase 1: contiguous read of 2304 floats
// (coalesced dwords), bf16 into LDS [ocl][ic*9+tap] with row pad 576->584
// (breaks the 288%32==0 bank alias). Phase 2: 288 ushort8 chunks, 8 LDS
// gathers each, coalesced 16B stores (4-chunk = 64B runs per (tap,ich)).
__global__ __launch_bounds__(256)
void reorder_w(const float* __restrict__ Wc, ushort* __restrict__ wout) {
    __shared__ ushort lw[4 * 584];          // 4672 B
    const int t   = threadIdx.x;
    const int e   = blockIdx.x >> 5;        // 0..3
    const int oc0 = (blockIdx.x & 31) * 4;  // 0,4,..,124
    const float* src = Wc + (size_t)(e * 128 + oc0) * 576;
#pragma unroll
    for (int k = 0; k < 9; ++k) {           // 9*256 = 2304 floats
        const int f   = k * 256 + t;
        const int ocl = f / 576;
        const int rem = f - ocl * 576;      // ic*9 + tap
        lw[ocl * 584 + rem] = f2bf(src[f]);
    }
    __syncthreads();
#pragma unroll
    for (int k = 0; k < 2; ++k) {
        const int n = k * 256 + t;          // 0..287 = tap(9) x ich(8) x ocl(4)
        if (n < 288) {
            const int ocl = n & 3, ich = (n >> 2) & 7, tap = n >> 5;
            ushort8 v;
#pragma unroll
            for (int icl = 0; icl < 8; ++icl)
                v[icl] = lw[ocl * 584 + (ich * 8 + icl) * 9 + tap];
            *(ushort8*)(wout +
                ((((size_t)(e * 9 + tap) * 8 + ich) * 128 + oc0 + ocl) * 8)) = v;
        }
    }
}

// ---------------- main kernel ----------------
__global__ __launch_bounds__(256, 4)
void moe_conv_mfma(const float* __restrict__ x, const int* __restrict__ idx,
                   const ushort* __restrict__ wre, const float* __restrict__ bc,
                   float* __restrict__ out) {
    __shared__ __align__(16) ushort xs[4 * 8 * 66 * 8];  // [r][ich][hc][icl] 33792 B
    __shared__ float bias[128];

    const int t = threadIdx.x;

    // T1: XCD c (= lin%8) owns contiguous work ids [c*128, c*128+128) = 4 whole
    // samples x 32 row-pairs, dispatched back-to-back -> halo + x-slice L2-hot.
    const int lin = blockIdx.x;                 // 0..1023
    const int nw  = (lin & 7) * 128 + (lin >> 3);
    const int b   = nw >> 5;                    // sample 0..31
    const int rp  = nw & 31;                    // row pair 0..31
    const int row0 = rp * 2;
    const int e    = ((unsigned)idx[b]) & 3;    // hardened expert index

    // --- per-lane MFMA coordinates ---
    const int lane31 = t & 31;
    const int lhi    = (t >> 5) & 1;
    const int wv     = t >> 6;            // 0..3
    const int w0     = wv & 1;            // oc half
    const int pr     = wv >> 1;           // output row within pair, 0..1

    // Per-lane weight base: element ((tap*8 + ks*2 + lhi)*128 + w0*64 + lane31)*8
    // = wsrc + s*2048 (+256 for a1), s = tap*4 + ks.
    const ushort* wsrc = wre + (size_t)e * 9 * 8192
                       + ((size_t)lhi * 128 + w0 * 64 + lane31) * 8;

    // issue step-0 A loads now: latency hides under x staging below
    short8 a0c = *(const short8*)(wsrc);
    short8 a1c = *(const short8*)(wsrc + 256);

    // --- halo-column zeros (hc = 0, 65) + bias stage ---
    if (t < 128) {  // r(4) x ich(8) x side(2) x q(2)
        const int r = t >> 5, rem = t & 31;
        const int ich = rem >> 2, side = (rem >> 1) & 1, q = rem & 1;
        const int hc = side ? 65 : 0;
        ushort4 z = {0, 0, 0, 0};
        *(ushort4*)&xs[(((r * 8 + ich) * 66 + hc) * 8 + q * 4)] = z;
    } else {
        bias[t - 128] = bc[e * OC + (t - 128)];
    }

    // --- x staging: fp32 [ic][h][w] -> bf16 [r(4)][ich][hc][icl] ---
    const float* xb = x + (size_t)b * IC * HH * WW;
    {
        const int gc   = t & 63;          // coalesced lane = w
        const int csel = t >> 6;          // 0..3
#pragma unroll
        for (int it = 0; it < 16; ++it) {
            const int combo = it * 4 + csel;       // 0..63 = r(4) x ich(8) x q(2)
            const int r = combo >> 4, rem = combo & 15;
            const int ich = rem >> 1, q = rem & 1;
            const int gr = row0 - 1 + r;
            ushort4 u = {0, 0, 0, 0};
            if ((unsigned)gr < (unsigned)HH) {
                const int ic0 = ich * 8 + q * 4;
                u.x = f2bf(xb[((ic0 + 0) * HH + gr) * WW + gc]);
                u.y = f2bf(xb[((ic0 + 1) * HH + gr) * WW + gc]);
                u.z = f2bf(xb[((ic0 + 2) * HH + gr) * WW + gc]);
                u.w = f2bf(xb[((ic0 + 3) * HH + gr) * WW + gc]);
            }
            *(ushort4*)&xs[(((r * 8 + ich) * 66 + (gc + 1)) * 8 + q * 4)] = u;
        }
    }

    float16 acc[2][2];
#pragma unroll
    for (int a = 0; a < 2; ++a)
#pragma unroll
        for (int cg = 0; cg < 2; ++cg)
#pragma unroll
            for (int r = 0; r < 16; ++r) acc[a][cg][r] = 0.0f;

    __syncthreads();   // the ONLY barrier: xs + bias visible to all waves

    // Lane-constant part of the xs B-fragment address; per-step remainder is a
    // compile-time constant folded into the ds_read offset immediate.
    const int xbase = ((pr * 8 + lhi) * 66 + lane31) * 8;

    // --- 36 free-running MFMA steps (tap = s>>2, ks = s&3), A dbuf'd 1 ahead ---
#pragma unroll
    for (int s = 0; s < 36; ++s) {
        const int tap = s >> 2, ks = s & 3;
        const int kh  = tap / 3, kw = tap - kh * 3;
        const int off = ((kh * 8 + ks * 2) * 66 + kw) * 8;   // step-const

        const short8 b0 = *(const short8*)&xs[xbase + off];
        const short8 b1 = *(const short8*)&xs[xbase + off + 256];  // +32 px

        short8 a0n, a1n;
        if (s < 35) {  // prefetch next step's A-frags; fly under the MFMAs
            a0n = *(const short8*)(wsrc + (s + 1) * 2048);
            a1n = *(const short8*)(wsrc + (s + 1) * 2048 + 256);
        }

        __builtin_amdgcn_s_setprio(1);
        acc[0][0] = __builtin_amdgcn_mfma_f32_32x32x16_bf16(a0c, b0, acc[0][0], 0, 0, 0);
        acc[0][1] = __builtin_amdgcn_mfma_f32_32x32x16_bf16(a0c, b1, acc[0][1], 0, 0, 0);
        acc[1][0] = __builtin_amdgcn_mfma_f32_32x32x16_bf16(a1c, b0, acc[1][0], 0, 0, 0);
        acc[1][1] = __builtin_amdgcn_mfma_f32_32x32x16_bf16(a1c, b1, acc[1][1], 0, 0, 0);
        __builtin_amdgcn_s_setprio(0);

        if (s < 35) { a0c = a0n; a1c = a1n; }
    }

    // --- epilogue: C/D layout col=lane&31, row=(reg&3)+8*(reg>>2)+4*(lane>>5) ---
#pragma unroll
    for (int a = 0; a < 2; ++a) {
        const int ocb = w0 * 64 + a * 32 + 4 * lhi;
#pragma unroll
        for (int reg = 0; reg < 16; ++reg) {
            const int oc = ocb + (reg & 3) + 8 * (reg >> 2);
            const float bv = bias[oc];
            const size_t base = (((size_t)b * OC + oc) * HH + (row0 + pr)) * WW;
            out[base + lane31]      = acc[a][0][reg] + bv;
            out[base + 32 + lane31] = acc[a][1][reg] + bv;
        }
    }
}

extern "C" void kernel_launch(void* const* d_in, const int* in_sizes, int n_in,
                              void* d_out, int out_size, void* d_ws, size_t ws_size,
                              hipStream_t stream) {
    const float* x   = (const float*)d_in[0];
    const int*   idx = (const int*)d_in[1];
    const float* Wc  = (const float*)d_in[2];
    const float* bc  = (const float*)d_in[3];
    float* out  = (float*)d_out;
    ushort* wre = (ushort*)d_ws;   // 294,912 bf16 = 576 KB scratch

    reorder_w<<<128, 256, 0, stream>>>(Wc, wre);    // 128*2304 = 294,912 = |Wc|
    moe_conv_mfma<<<1024, 256, 0, stream>>>(x, idx, wre, bc, out);
}